// Round 4
// baseline (560.677 us; speedup 1.0000x reference)
//
#include <hip/hip_runtime.h>
#include <hip/hip_bf16.h>
#include <hip/hip_fp8.h>

#define N_NODES 100000
#define N_EDGES 3200000
#define IN_DIM  128
#define HID     32
#define NCLUS   30
#define EDGE_BLOCKS 12500 // ceil(3200000/256)
#define GRP_BLOCKS  12500 // ceil(100000/8)

// ---- counting-sort geometry (LDS-atomic CSR build; global atomics eliminated) ----
#define BUCK_SHIFT 7
#define BUCK_W     128                 // nodes per bucket
#define NBUCK      782                 // ceil(100000/128)
#define PB         512                 // pass-1 blocks
#define EPB        6250                // edges per pass-1 block (512*6250 = 3.2M exact)
#define SEG_CAP    8192                // LDS stage capacity per bucket (avg 4092, 64 sigma margin)

// ---- gemm1 register-blocked geometry ----
#define G1_PAIRS   32                  // row-pairs per wave
#define G1_BLOCKS  391                 // ceil(100000/256)

__device__ __forceinline__ float bf2f(__hip_bfloat16 v) { return __bfloat162float(v); }

// fp8 e4m3 (OCP) encode/decode via HW cvt
__device__ __forceinline__ unsigned char enc8(float v) {
  __hip_fp8_e4m3 t(v); return (unsigned char)t.__x;
}
__device__ __forceinline__ float dec8(unsigned b) {
  __hip_fp8_e4m3 t; t.__x = (__hip_fp8_storage_t)b; return (float)t;
}
__device__ __forceinline__ float dot4_fp8(unsigned a, unsigned b) {
  float r = 0.0f;
  #pragma unroll
  for (int k = 0; k < 4; k++)
    r += dec8((a >> (8 * k)) & 0xffu) * dec8((b >> (8 * k)) & 0xffu);
  return r;
}

// edge_index accessor: f=0 -> int32 layout, f=1 -> int64 layout (read low word)
__device__ __forceinline__ int edge_at(const int* ei, int row, int e, int f) {
  int v = ei[(row * N_EDGES + e) << f];
  return min(max(v, 0), N_NODES - 1);
}

// ---- detect int32 vs int64 edge_index ----
__global__ void k_detect(const unsigned int* ei, int* flag) {
  if (threadIdx.x == 0) {
    int zeros = 0;
    for (int i = 1; i < 128; i += 2) zeros += (ei[i] == 0u) ? 1 : 0;
    *flag = (zeros >= 48) ? 1 : 0;
  }
}

// ---- zero loss scalars (CSR path needs no counter zeroing: pass2 writes all nodes) ----
__global__ void k_zerosc(float* colsum, double* msed) {
  int t = threadIdx.x;
  if (t < 32) colsum[t] = 0.0f;
  if (t == 32) *msed = 0.0;
}

// ---- zero cnt + loss scalars (fallback path) ----
__global__ void k_zeroall(int* cnt, float* colsum, double* msed) {
  int t = blockIdx.x * blockDim.x + threadIdx.x;
  if (t < N_NODES) cnt[t] = 0;
  if (t < 32) colsum[t] = 0.0f;
  if (t == 32) *msed = 0.0;
}

// ---- GEMM1 v3: register-blocked + PRE-SCALED by dinv[n] (runs after the sort).
//      Eliminates the per-edge dinv[s] gather in agg1 (3.2M loads + a latency level). ----
__global__ void __launch_bounds__(256) k_gemm1r(const float* x, const float* W1,
                                                const float* dinv, __hip_bfloat16* G1) {
  int lane = threadIdx.x & 63;
  int wid  = threadIdx.x >> 6;
  int j = lane & 31;                     // output col
  int h = lane >> 5;                     // k-half: 0 -> k in [0,64), 1 -> [64,128)
  float w[64];
  #pragma unroll
  for (int k = 0; k < 64; k++) w[k] = W1[(h * 64 + k) * HID + j];   // L1-hot, coalesced per half
  int base = (blockIdx.x * 4 + wid) * (2 * G1_PAIRS);
  for (int p = 0; p < G1_PAIRS; p++) {
    int n0 = base + 2 * p;
    if (n0 >= N_NODES) return;
    int n1 = n0 + 1;                     // N_NODES even -> always valid
    const float4* xa = (const float4*)(x + (size_t)n0 * IN_DIM + h * 64);
    const float4* xb = (const float4*)(x + (size_t)n1 * IN_DIM + h * 64);
    float accA = 0.0f, accB = 0.0f;
    #pragma unroll
    for (int c = 0; c < 16; c++) {
      float4 a = xa[c];
      float4 b = xb[c];
      accA += a.x * w[4*c] + a.y * w[4*c+1] + a.z * w[4*c+2] + a.w * w[4*c+3];
      accB += b.x * w[4*c] + b.y * w[4*c+1] + b.z * w[4*c+2] + b.w * w[4*c+3];
    }
    accA += __shfl_xor(accA, 32, 64);    // combine K-halves
    accB += __shfl_xor(accB, 32, 64);
    if (h == 0) G1[n0 * 32 + j] = __float2bfloat16(accA * dinv[n0]);
    else        G1[n1 * 32 + j] = __float2bfloat16(accB * dinv[n1]);
  }
}

// ---- sort pass 1a: per-block LDS bucket histogram (dst>>7), dump H[p][*] ----
__global__ void __launch_bounds__(256) k_hist(const int* ei, const int* flag, int* H) {
  __shared__ int h[NBUCK];
  int t = threadIdx.x, p = blockIdx.x;
  for (int i = t; i < NBUCK; i += 256) h[i] = 0;
  __syncthreads();
  int f = *flag;
  int base = p * EPB;
  for (int i = t; i < EPB; i += 256) {
    int d = edge_at(ei, 1, base + i, f);
    atomicAdd(&h[d >> BUCK_SHIFT], 1);       // ds_add, on-CU
  }
  __syncthreads();
  for (int i = t; i < NBUCK; i += 256) H[p * NBUCK + i] = h[i];
}

// ---- sort scan A: column-scan of H over PB blocks -> exclusive in place + bucket totals ----
__global__ void __launch_bounds__(PB) k_hscan(int* H, int* tot) {
  __shared__ int s[PB];
  int b = blockIdx.x, t = threadIdx.x;
  int v = H[t * NBUCK + b];
  s[t] = v; __syncthreads();
  for (int off = 1; off < PB; off <<= 1) {
    int u = (t >= off) ? s[t - off] : 0;
    __syncthreads();
    s[t] += u;
    __syncthreads();
  }
  H[t * NBUCK + b] = s[t] - v;               // exclusive prefix within bucket column
  if (t == PB - 1) tot[b] = s[t];
}

// ---- sort scan B: exclusive scan of bucket totals -> bstart[0..NBUCK] ----
__global__ void __launch_bounds__(1024) k_bscan(const int* tot, int* bstart) {
  __shared__ int s[1024];
  int t = threadIdx.x;
  int v = (t < NBUCK) ? tot[t] : 0;
  s[t] = v; __syncthreads();
  for (int off = 1; off < 1024; off <<= 1) {
    int u = (t >= off) ? s[t - off] : 0;
    __syncthreads();
    s[t] += u;
    __syncthreads();
  }
  if (t < NBUCK) bstart[t] = s[t] - v;
  if (t == NBUCK - 1) bstart[NBUCK] = s[t];  // = N_EDGES
}

// ---- sort pass 1b: scatter packed (src<<7 | dst&127) to bucket-segmented order ----
__global__ void __launch_bounds__(256) k_scat1(const int* ei, const int* flag, const int* H,
                                               const int* bstart, unsigned* sorted) {
  __shared__ int cur[NBUCK];
  int t = threadIdx.x, p = blockIdx.x;
  for (int i = t; i < NBUCK; i += 256) cur[i] = bstart[i] + H[p * NBUCK + i];
  __syncthreads();
  int f = *flag;
  int base = p * EPB;
  for (int i = t; i < EPB; i += 256) {
    int e = base + i;
    int s = edge_at(ei, 0, e, f);
    int d = edge_at(ei, 1, e, f);
    int slot = atomicAdd(&cur[d >> BUCK_SHIFT], 1);   // ds_add_rtn, on-CU
    sorted[slot] = ((unsigned)s << BUCK_SHIFT) | (unsigned)(d & (BUCK_W - 1));
  }
}

// ---- sort pass 2: one block per bucket: LDS count + scan -> cnt/cursor/dinv + exact CSR ----
__global__ void __launch_bounds__(256) k_pass2(const unsigned* sorted, const int* bstart,
                                               int* cnt, int* cursor, float* dinv, int* csr) {
  __shared__ unsigned se[SEG_CAP];
  __shared__ int scnt[BUCK_W], soff[BUCK_W], scur[BUCK_W];
  int b = blockIdx.x, t = threadIdx.x;
  int s0 = bstart[b], s1 = bstart[b + 1], len = s1 - s0;
  for (int i = t; i < len && i < SEG_CAP; i += 256) se[i] = sorted[s0 + i];
  if (t < BUCK_W) scnt[t] = 0;
  __syncthreads();
  for (int i = t; i < len; i += 256) {
    unsigned u = (i < SEG_CAP) ? se[i] : sorted[s0 + i];
    atomicAdd(&scnt[u & (BUCK_W - 1)], 1);
  }
  __syncthreads();
  int c = (t < BUCK_W) ? scnt[t] : 0;
  if (t < BUCK_W) soff[t] = c;
  __syncthreads();
  for (int off = 1; off < BUCK_W; off <<= 1) {
    int u = 0;
    if (t >= off && t < BUCK_W) u = soff[t - off];
    __syncthreads();
    if (t < BUCK_W) soff[t] += u;
    __syncthreads();
  }
  if (t < BUCK_W) {
    int ex = soff[t] - c;                    // exclusive local offset
    int node = (b << BUCK_SHIFT) + t;
    if (node < N_NODES) {
      cnt[node] = c;
      cursor[node] = s0 + ex;
      dinv[node] = rsqrtf((float)(c + 1));
    }
    scur[t] = ex;                            // running cursor starts at exclusive offset
  }
  __syncthreads();
  for (int i = t; i < len; i += 256) {
    unsigned u = (i < SEG_CAP) ? se[i] : sorted[s0 + i];
    int dl = u & (BUCK_W - 1);
    int r = atomicAdd(&scur[dl], 1);
    csr[s0 + r] = (int)(u >> BUCK_SHIFT);
  }
}

// ---- plain count (fallback path) ----
__global__ void k_count(const int* ei, const int* flag, int* cnt) {
  int e = blockIdx.x * blockDim.x + threadIdx.x;
  if (e >= N_EDGES) return;
  int f = *flag;
  atomicAdd(&cnt[edge_at(ei, 1, e, f)], 1);
}

// ---- dinv (fallback path) ----
__global__ void k_dinv(const int* cnt, float* dinv) {
  int t = blockIdx.x * blockDim.x + threadIdx.x;
  if (t < N_NODES) dinv[t] = rsqrtf((float)(cnt[t] + 1));
}

// ---- FUSED agg1 + gemm2: gather pre-scaled G1 -> h in reg ->
//      G2[n,j] = (sum_k shfl(h,k)*W2[k,j]) * dinv[n], bf16 out.
//      csr read amortized 32x: lane j loads csr[st+i+j] (coalesced), shfl-broadcast. ----
__global__ void __launch_bounds__(256) k_agg1f(const __hip_bfloat16* G, const int* cursor,
                                               const int* cnt, const int* csr, const float* dinv,
                                               const float* b1, const float* W2,
                                               __hip_bfloat16* G2) {
  int j = threadIdx.x & 31, g = threadIdx.x >> 5;
  int n = blockIdx.x * 8 + g;
  if (n >= N_NODES) return;
  float w2c[HID];
  #pragma unroll
  for (int k = 0; k < HID; k++) w2c[k] = (j < NCLUS) ? W2[k * NCLUS + j] : 0.0f;
  int len = cnt[n];
  int st = cursor[n];
  float dn = dinv[n];
  float acc = bf2f(G[n * 32 + j]);        // self loop (pre-scaled)
  int i = 0;
  for (; i + 32 <= len; i += 32) {
    int sl = csr[st + i + j];             // 1 coalesced load serves 32 edges
    #pragma unroll
    for (int q = 0; q < 32; q++) {
      int sq = __shfl(sl, q, 32);
      acc += bf2f(G[sq * 32 + j]);        // 32 independent row loads in flight
    }
  }
  for (; i + 8 <= len; i += 8) {
    int s[8];
    #pragma unroll
    for (int q = 0; q < 8; q++) s[q] = csr[st + i + q];
    #pragma unroll
    for (int q = 0; q < 8; q++) acc += bf2f(G[s[q] * 32 + j]);
  }
  for (; i < len; i++) acc += bf2f(G[csr[st + i] * 32 + j]);
  float h = fmaxf(dn * acc + b1[j], 0.0f);
  float g2 = 0.0f;
  #pragma unroll
  for (int k = 0; k < HID; k++) g2 += __shfl(h, k, 32) * w2c[k];
  G2[n * 32 + j] = __float2bfloat16((j < NCLUS) ? g2 * dn : 0.0f);
}

// ---- CSR agg layer2 (pre-scaled G2), shfl-amortized csr + softmax -> out + fx8 ----
__global__ void __launch_bounds__(256) k_agg2c(const __hip_bfloat16* G, const int* cursor,
                                               const int* cnt, const int* csr, const float* dinv,
                                               const float* b2, float* outp, unsigned char* fx8) {
  int j = threadIdx.x & 31, g = threadIdx.x >> 5;
  int n = blockIdx.x * 8 + g;
  if (n >= N_NODES) return;
  int len = cnt[n];
  int st = cursor[n];
  float acc = bf2f(G[n * 32 + j]);
  int i = 0;
  for (; i + 32 <= len; i += 32) {
    int sl = csr[st + i + j];
    #pragma unroll
    for (int q = 0; q < 32; q++) {
      int sq = __shfl(sl, q, 32);
      acc += bf2f(G[sq * 32 + j]);
    }
  }
  for (; i + 8 <= len; i += 8) {
    int s[8];
    #pragma unroll
    for (int q = 0; q < 8; q++) s[q] = csr[st + i + q];
    #pragma unroll
    for (int q = 0; q < 8; q++) acc += bf2f(G[s[q] * 32 + j]);
  }
  for (; i < len; i++) acc += bf2f(G[csr[st + i] * 32 + j]);
  bool act = (j < NCLUS);
  float logit = act ? fminf(fmaxf(dinv[n] * acc + b2[j], -80.0f), 80.0f) : -1e30f;
  float m = logit;
  #pragma unroll
  for (int mask = 16; mask > 0; mask >>= 1) m = fmaxf(m, __shfl_xor(m, mask, 32));
  float ex = act ? __expf(logit - m) : 0.0f;
  float ssum = ex;
  #pragma unroll
  for (int mask = 16; mask > 0; mask >>= 1) ssum += __shfl_xor(ssum, mask, 32);
  float fx = ex / fmaxf(ssum, 1e-30f);
  if (act) outp[n * NCLUS + j] = fx;
  fx8[n * 32 + j] = enc8(act ? fx : 0.0f);
}

// ---- fallback fp32 kernels (atomic path) ----
__global__ void __launch_bounds__(256) k_gemm1s(const float* x, const float* W1,
                                                const float* dinv, float* G1) {
  __shared__ float Ws[IN_DIM * HID];
  int tid = threadIdx.x;
  for (int i = tid; i < IN_DIM * HID; i += 256) Ws[i] = W1[i];
  __syncthreads();
  int j = tid & 31, r = tid >> 5;
  int n = blockIdx.x * 8 + r;
  if (n >= N_NODES) return;
  const float* xr = x + (size_t)n * IN_DIM;
  float acc = 0.0f;
  #pragma unroll
  for (int k = 0; k < IN_DIM; k++) acc += xr[k] * Ws[k * HID + j];
  G1[n * 32 + j] = acc * dinv[n];
}

__global__ void __launch_bounds__(256) k_gemm2s(const float* h, const float* W2,
                                                const float* dinv, float* G2) {
  __shared__ float Ws[HID * 32];
  int tid = threadIdx.x;
  for (int i = tid; i < HID * 32; i += 256) Ws[i] = 0.0f;
  __syncthreads();
  for (int i = tid; i < HID * NCLUS; i += 256) {
    int k = i / NCLUS, j = i % NCLUS;
    Ws[k * 32 + j] = W2[i];
  }
  __syncthreads();
  int j = tid & 31, r = tid >> 5;
  int n = blockIdx.x * 8 + r;
  if (n >= N_NODES) return;
  const float* hr = h + (size_t)n * 32;
  float acc = 0.0f;
  #pragma unroll
  for (int k = 0; k < HID; k++) acc += hr[k] * Ws[k * 32 + j];
  G2[n * 32 + j] = (j < NCLUS) ? acc * dinv[n] : 0.0f;
}

__global__ void __launch_bounds__(256) k_eagg2(const int* ei, const int* flag,
                                               const float* G, float* D) {
  int j = threadIdx.x & 31, g = threadIdx.x >> 5;
  int f = *flag;
  for (int e = blockIdx.x * 8 + g; e < N_EDGES; e += gridDim.x * 8) {
    int s = edge_at(ei, 0, e, f);
    int d = edge_at(ei, 1, e, f);
    atomicAdd(&D[d * 32 + j], G[s * 32 + j]);
  }
}

__global__ void k_relu2(const float* A, const float* dinv, const float* b1, float* G) {
  int t = blockIdx.x * blockDim.x + threadIdx.x;
  if (t >= N_NODES * 32) return;
  int n = t >> 5, j = t & 31;
  G[t] = fmaxf(dinv[n] * (A[t] + G[t]) + b1[j], 0.0f);
}

__global__ void __launch_bounds__(256) k_softmax2(const float* S, const float* G2, const float* dinv,
                                                  const float* b2, float* outp) {
  int n = blockIdx.x * blockDim.x + threadIdx.x;
  if (n >= N_NODES) return;
  float di = dinv[n];
  float lg[NCLUS];
  float m = -1e30f;
  #pragma unroll
  for (int j = 0; j < NCLUS; j++) {
    float v = di * (S[n * 32 + j] + G2[n * 32 + j]) + b2[j];
    v = fminf(fmaxf(v, -80.0f), 80.0f);
    lg[j] = v; m = fmaxf(m, v);
  }
  float ssum = 0.0f;
  #pragma unroll
  for (int j = 0; j < NCLUS; j++) { lg[j] = __expf(lg[j] - m); ssum += lg[j]; }
  float inv = 1.0f / ssum;
  #pragma unroll
  for (int j = 0; j < NCLUS; j++) outp[n * NCLUS + j] = lg[j] * inv;
}

// ---- out (fp32, stride 30) -> fx8 (fp8, stride 32), fallback path ----
__global__ void k_fx8(const float* outp, unsigned char* fx8) {
  int t = blockIdx.x * blockDim.x + threadIdx.x;
  if (t >= N_NODES * 32) return;
  int n = t >> 5, j = t & 31;
  fx8[t] = enc8((j < NCLUS) ? outp[n * NCLUS + j] : 0.0f);
}

// ---- edge MSE, lane-per-edge over fp8 rows (32 B/row, L2-resident 3.2 MB table) ----
__global__ void __launch_bounds__(256) k_msef3(const int* ei, const float* ep,
                                               const uint4* fx8, const int* flag,
                                               double* msed) {
  int f = *flag;
  int tid = blockIdx.x * blockDim.x + threadIdx.x;
  float local = 0.0f;
  for (int e = tid; e < N_EDGES; e += gridDim.x * blockDim.x) {
    int s = edge_at(ei, 0, e, f);
    int d = edge_at(ei, 1, e, f);
    const uint4* rs = fx8 + s * 2;   // 32 B row = 2 x uint4
    const uint4* rd = fx8 + d * 2;
    uint4 a0 = rs[0], a1 = rs[1];
    uint4 b0 = rd[0], b1 = rd[1];
    float acc;
    acc  = dot4_fp8(a0.x, b0.x) + dot4_fp8(a0.y, b0.y)
         + dot4_fp8(a0.z, b0.z) + dot4_fp8(a0.w, b0.w);
    acc += dot4_fp8(a1.x, b1.x) + dot4_fp8(a1.y, b1.y)
         + dot4_fp8(a1.z, b1.z) + dot4_fp8(a1.w, b1.w);
    float diff = acc - ep[e];
    local += diff * diff;
  }
  __shared__ float sd[256];
  sd[threadIdx.x] = local; __syncthreads();
  for (int off = 128; off > 0; off >>= 1) {
    if (threadIdx.x < off) sd[threadIdx.x] += sd[threadIdx.x + off];
    __syncthreads();
  }
  if (threadIdx.x == 0) atomicAdd(msed, (double)sd[0]);
}

// ---- column sums of log(1-FX^2) ----
__global__ void __launch_bounds__(256) k_colsumf(const float* FX, float* colsum) {
  __shared__ float sd[256];
  int tid = threadIdx.x;
  int j = tid & 31, g = tid >> 5;
  float local = 0.0f;
  if (j < NCLUS) {
    for (int n = blockIdx.x * 8 + g; n < N_NODES; n += gridDim.x * 8) {
      float v = FX[n * NCLUS + j];
      local += log1pf(-v * v);
    }
  }
  sd[tid] = local; __syncthreads();
  if (tid < 32) {
    float s = 0.0f;
    #pragma unroll
    for (int gg = 0; gg < 8; gg++) s += sd[tid + 32 * gg];
    if (tid < NCLUS) atomicAdd(&colsum[tid], s);
  }
}

// ---- final loss ----
__global__ void k_final(const float* colsum, const double* msed, float* out) {
  int tid = threadIdx.x;
  float v = 0.0f;
  if (tid < NCLUS) v = logf(1.0001f - __expf(colsum[tid]));
  #pragma unroll
  for (int mask = 32; mask > 0; mask >>= 1) v += __shfl_xor(v, mask, 64);
  if (tid == 0) {
    float preg = -v;
    float msev = (float)(*msed / (double)N_EDGES);
    out[(size_t)N_NODES * NCLUS] = msev + 0.01f * preg;
  }
}

extern "C" void kernel_launch(void* const* d_in, const int* in_sizes, int n_in,
                              void* d_out, int out_size, void* d_ws, size_t ws_size,
                              hipStream_t stream) {
  const float* x  = (const float*)d_in[0];
  const int*   ei = (const int*)d_in[1];
  const float* ep = (const float*)d_in[2];
  const float* W1 = (const float*)d_in[3];
  const float* b1 = (const float*)d_in[4];
  const float* W2 = (const float*)d_in[5];
  const float* b2 = (const float*)d_in[6];
  float* out = (float*)d_out;   // fp32: FX[100000*30] then loss scalar

  char* ws = (char*)d_ws;
  size_t off = 0;
  auto alloc = [&](size_t bytes) { size_t o = off; off += (bytes + 255) & ~(size_t)255; return o; };

  size_t o_hdr  = alloc(1024);                       // flag@0, msed@8(double), colsum@256
  size_t o_cnt  = alloc((size_t)N_NODES * 4);
  size_t o_dinv = alloc((size_t)N_NODES * 4);
  size_t o_B1   = alloc((size_t)N_NODES * 32 * 4);   // CSR: G1 bf16 [0,6.4M) + H/tot/bstart [6.4M,...)
  size_t o_B2   = alloc((size_t)N_NODES * 32 * 4);   // CSR: sorted [0,12.8M) -> later fx8[0,3.2M)+G2[3.2M,9.6M)

  int*    flag   = (int*)(ws + o_hdr);
  double* msed   = (double*)(ws + o_hdr + 8);
  float*  colsum = (float*)(ws + o_hdr + 256);
  int*    cnt    = (int*)(ws + o_cnt);
  float*  dinv   = (float*)(ws + o_dinv);
  float*  B1f    = (float*)(ws + o_B1);
  float*  B2f    = (float*)(ws + o_B2);
  __hip_bfloat16* B1b = (__hip_bfloat16*)(ws + o_B1);
  unsigned char*  B2c = (unsigned char*)(ws + o_B2);

  const int nodeBlocks = (N_NODES + 255) / 256;
  const int edgeBlocks = EDGE_BLOCKS;
  const int grpBlocks  = GRP_BLOCKS;
  const int elemBlocks = (N_NODES * 32 + 255) / 256;

  k_detect<<<1, 64, 0, stream>>>((const unsigned int*)ei, flag);

  size_t o_cursor = alloc((size_t)N_NODES * 4);
  size_t o_csr    = alloc((size_t)N_EDGES * 4);
  bool use_csr = (off <= ws_size);

  const unsigned char* fx8;

  if (use_csr) {
    int* cursor = (int*)(ws + o_cursor);
    int* csr    = (int*)(ws + o_csr);
    // overlays inside B1 upper half (G1 bf16 occupies [0, 6.4M))
    int* H      = (int*)(ws + o_B1 + 6400000);                 // 512*782*4 = 1.6 MB
    int* tot    = (int*)(ws + o_B1 + 6400000 + 1601536);       // 782*4
    int* bstart = (int*)(ws + o_B1 + 6400000 + 1605632);       // 783*4
    unsigned* sorted = (unsigned*)B2c;                          // B2 [0,12.8M), dead after pass2

    k_zerosc<<<1, 64, 0, stream>>>(colsum, msed);

    // LDS-atomic counting sort -> cnt, cursor, dinv, csr (zero global atomics)
    k_hist <<<PB, 256, 0, stream>>>(ei, flag, H);
    k_hscan<<<NBUCK, PB, 0, stream>>>(H, tot);
    k_bscan<<<1, 1024, 0, stream>>>(tot, bstart);
    k_scat1<<<PB, 256, 0, stream>>>(ei, flag, H, bstart, sorted);
    k_pass2<<<NBUCK, 256, 0, stream>>>(sorted, bstart, cnt, cursor, dinv, csr);

    // gemm1 after the sort: writes dinv-pre-scaled G1
    __hip_bfloat16* G1b = B1b;
    k_gemm1r<<<G1_BLOCKS, 256, 0, stream>>>(x, W1, dinv, G1b);

    __hip_bfloat16* G2b = (__hip_bfloat16*)(ws + o_B2 + (size_t)N_NODES * 32); // [3.2M,9.6M)
    unsigned char*  fx  = B2c;                                                  // [0,3.2M)

    k_agg1f<<<grpBlocks, 256, 0, stream>>>(G1b, cursor, cnt, csr, dinv, b1, W2, G2b);
    k_agg2c<<<grpBlocks, 256, 0, stream>>>(G2b, cursor, cnt, csr, dinv, b2, out, fx);
    fx8 = fx;
  } else {
    k_zeroall<<<nodeBlocks, 256, 0, stream>>>(cnt, colsum, msed);
    k_count<<<edgeBlocks, 256, 0, stream>>>(ei, flag, cnt);
    k_dinv<<<nodeBlocks, 256, 0, stream>>>(cnt, dinv);
    k_gemm1s<<<grpBlocks, 256, 0, stream>>>(x, W1, dinv, B1f);
    hipMemsetAsync(B2f, 0, (size_t)N_NODES * 32 * 4, stream);
    k_eagg2<<<8192, 256, 0, stream>>>(ei, flag, B1f, B2f);
    k_relu2<<<elemBlocks, 256, 0, stream>>>(B2f, dinv, b1, B1f);
    k_gemm2s<<<grpBlocks, 256, 0, stream>>>(B1f, W2, dinv, B2f);
    hipMemsetAsync(B1f, 0, (size_t)N_NODES * 32 * 4, stream);
    k_eagg2<<<8192, 256, 0, stream>>>(ei, flag, B2f, B1f);
    k_softmax2<<<nodeBlocks, 256, 0, stream>>>(B1f, B2f, dinv, b2, out);
    k_fx8<<<elemBlocks, 256, 0, stream>>>(out, (unsigned char*)B1b);
    fx8 = (const unsigned char*)B1b;
  }

  // loss
  k_msef3<<<4096, 256, 0, stream>>>(ei, ep, (const uint4*)fx8, flag, msed);
  k_colsumf<<<256, 256, 0, stream>>>(out, colsum);
  k_final<<<1, 64, 0, stream>>>(colsum, msed, out);
}

// Round 5
// 500.111 us; speedup vs baseline: 1.1211x; 1.1211x over previous
//
#include <hip/hip_runtime.h>
#include <hip/hip_bf16.h>
#include <hip/hip_fp8.h>

#define N_NODES 100000
#define N_EDGES 3200000
#define IN_DIM  128
#define HID     32
#define NCLUS   30
#define EDGE_BLOCKS 12500 // ceil(3200000/256)
#define GRP_BLOCKS  12500 // ceil(100000/8)

// ---- counting-sort geometry (LDS-atomic CSR build; global atomics eliminated) ----
#define BUCK_SHIFT 7
#define BUCK_W     128                 // nodes per bucket
#define NBUCK      782                 // ceil(100000/128)
#define PB         512                 // pass-1 blocks
#define EPB        6250                // edges per pass-1 block (512*6250 = 3.2M exact)
#define SEG_CAP    8192                // LDS stage capacity per bucket (avg 4092, 64 sigma margin)

// ---- gemm1 register-blocked geometry ----
#define G1_PAIRS   32                  // row-pairs per wave
#define G1_BLOCKS  391                 // ceil(100000/256)

__device__ __forceinline__ float bf2f(__hip_bfloat16 v) { return __bfloat162float(v); }

// fp8 e4m3 (OCP) encode/decode via HW cvt
__device__ __forceinline__ unsigned char enc8(float v) {
  __hip_fp8_e4m3 t(v); return (unsigned char)t.__x;
}
__device__ __forceinline__ float dec8(unsigned b) {
  __hip_fp8_e4m3 t; t.__x = (__hip_fp8_storage_t)b; return (float)t;
}
__device__ __forceinline__ float dot4_fp8(unsigned a, unsigned b) {
  float r = 0.0f;
  #pragma unroll
  for (int k = 0; k < 4; k++)
    r += dec8((a >> (8 * k)) & 0xffu) * dec8((b >> (8 * k)) & 0xffu);
  return r;
}

// edge_index accessor: f=0 -> int32 layout, f=1 -> int64 layout (read low word)
__device__ __forceinline__ int edge_at(const int* ei, int row, int e, int f) {
  int v = ei[(row * N_EDGES + e) << f];
  return min(max(v, 0), N_NODES - 1);
}

// ---- detect int32 vs int64 edge_index ----
__global__ void k_detect(const unsigned int* ei, int* flag) {
  if (threadIdx.x == 0) {
    int zeros = 0;
    for (int i = 1; i < 128; i += 2) zeros += (ei[i] == 0u) ? 1 : 0;
    *flag = (zeros >= 48) ? 1 : 0;
  }
}

// ---- zero loss scalars (CSR path needs no counter zeroing: pass2 writes all nodes) ----
__global__ void k_zerosc(float* colsum, double* msed) {
  int t = threadIdx.x;
  if (t < 32) colsum[t] = 0.0f;
  if (t == 32) *msed = 0.0;
}

// ---- zero cnt + loss scalars (fallback path) ----
__global__ void k_zeroall(int* cnt, float* colsum, double* msed) {
  int t = blockIdx.x * blockDim.x + threadIdx.x;
  if (t < N_NODES) cnt[t] = 0;
  if (t < 32) colsum[t] = 0.0f;
  if (t == 32) *msed = 0.0;
}

// ---- GEMM1 v3: register-blocked + PRE-SCALED by dinv[n] (runs after the sort).
//      Eliminates the per-edge dinv[s] gather in agg1 (3.2M loads + a latency level). ----
__global__ void __launch_bounds__(256) k_gemm1r(const float* x, const float* W1,
                                                const float* dinv, __hip_bfloat16* G1) {
  int lane = threadIdx.x & 63;
  int wid  = threadIdx.x >> 6;
  int j = lane & 31;                     // output col
  int h = lane >> 5;                     // k-half: 0 -> k in [0,64), 1 -> [64,128)
  float w[64];
  #pragma unroll
  for (int k = 0; k < 64; k++) w[k] = W1[(h * 64 + k) * HID + j];   // L1-hot, coalesced per half
  int base = (blockIdx.x * 4 + wid) * (2 * G1_PAIRS);
  for (int p = 0; p < G1_PAIRS; p++) {
    int n0 = base + 2 * p;
    if (n0 >= N_NODES) return;
    int n1 = n0 + 1;                     // N_NODES even -> always valid
    const float4* xa = (const float4*)(x + (size_t)n0 * IN_DIM + h * 64);
    const float4* xb = (const float4*)(x + (size_t)n1 * IN_DIM + h * 64);
    float accA = 0.0f, accB = 0.0f;
    #pragma unroll
    for (int c = 0; c < 16; c++) {
      float4 a = xa[c];
      float4 b = xb[c];
      accA += a.x * w[4*c] + a.y * w[4*c+1] + a.z * w[4*c+2] + a.w * w[4*c+3];
      accB += b.x * w[4*c] + b.y * w[4*c+1] + b.z * w[4*c+2] + b.w * w[4*c+3];
    }
    accA += __shfl_xor(accA, 32, 64);    // combine K-halves
    accB += __shfl_xor(accB, 32, 64);
    if (h == 0) G1[n0 * 32 + j] = __float2bfloat16(accA * dinv[n0]);
    else        G1[n1 * 32 + j] = __float2bfloat16(accB * dinv[n1]);
  }
}

// ---- sort pass 1a: per-block LDS bucket histogram (dst>>7), dump H[p][*] ----
__global__ void __launch_bounds__(256) k_hist(const int* ei, const int* flag, int* H) {
  __shared__ int h[NBUCK];
  int t = threadIdx.x, p = blockIdx.x;
  for (int i = t; i < NBUCK; i += 256) h[i] = 0;
  __syncthreads();
  int f = *flag;
  int base = p * EPB;
  for (int i = t; i < EPB; i += 256) {
    int d = edge_at(ei, 1, base + i, f);
    atomicAdd(&h[d >> BUCK_SHIFT], 1);       // ds_add, on-CU
  }
  __syncthreads();
  for (int i = t; i < NBUCK; i += 256) H[p * NBUCK + i] = h[i];
}

// ---- sort scan A: column-scan of H over PB blocks -> exclusive in place + bucket totals ----
__global__ void __launch_bounds__(PB) k_hscan(int* H, int* tot) {
  __shared__ int s[PB];
  int b = blockIdx.x, t = threadIdx.x;
  int v = H[t * NBUCK + b];
  s[t] = v; __syncthreads();
  for (int off = 1; off < PB; off <<= 1) {
    int u = (t >= off) ? s[t - off] : 0;
    __syncthreads();
    s[t] += u;
    __syncthreads();
  }
  H[t * NBUCK + b] = s[t] - v;               // exclusive prefix within bucket column
  if (t == PB - 1) tot[b] = s[t];
}

// ---- sort scan B: exclusive scan of bucket totals -> bstart[0..NBUCK] ----
__global__ void __launch_bounds__(1024) k_bscan(const int* tot, int* bstart) {
  __shared__ int s[1024];
  int t = threadIdx.x;
  int v = (t < NBUCK) ? tot[t] : 0;
  s[t] = v; __syncthreads();
  for (int off = 1; off < 1024; off <<= 1) {
    int u = (t >= off) ? s[t - off] : 0;
    __syncthreads();
    s[t] += u;
    __syncthreads();
  }
  if (t < NBUCK) bstart[t] = s[t] - v;
  if (t == NBUCK - 1) bstart[NBUCK] = s[t];  // = N_EDGES
}

// ---- sort pass 1b: scatter packed (src<<7 | dst&127) to bucket-segmented order ----
__global__ void __launch_bounds__(256) k_scat1(const int* ei, const int* flag, const int* H,
                                               const int* bstart, unsigned* sorted) {
  __shared__ int cur[NBUCK];
  int t = threadIdx.x, p = blockIdx.x;
  for (int i = t; i < NBUCK; i += 256) cur[i] = bstart[i] + H[p * NBUCK + i];
  __syncthreads();
  int f = *flag;
  int base = p * EPB;
  for (int i = t; i < EPB; i += 256) {
    int e = base + i;
    int s = edge_at(ei, 0, e, f);
    int d = edge_at(ei, 1, e, f);
    int slot = atomicAdd(&cur[d >> BUCK_SHIFT], 1);   // ds_add_rtn, on-CU
    sorted[slot] = ((unsigned)s << BUCK_SHIFT) | (unsigned)(d & (BUCK_W - 1));
  }
}

// ---- sort pass 2: one block per bucket: LDS count + scan -> cnt/cursor/dinv + exact CSR ----
__global__ void __launch_bounds__(256) k_pass2(const unsigned* sorted, const int* bstart,
                                               int* cnt, int* cursor, float* dinv, int* csr) {
  __shared__ unsigned se[SEG_CAP];
  __shared__ int scnt[BUCK_W], soff[BUCK_W], scur[BUCK_W];
  int b = blockIdx.x, t = threadIdx.x;
  int s0 = bstart[b], s1 = bstart[b + 1], len = s1 - s0;
  for (int i = t; i < len && i < SEG_CAP; i += 256) se[i] = sorted[s0 + i];
  if (t < BUCK_W) scnt[t] = 0;
  __syncthreads();
  for (int i = t; i < len; i += 256) {
    unsigned u = (i < SEG_CAP) ? se[i] : sorted[s0 + i];
    atomicAdd(&scnt[u & (BUCK_W - 1)], 1);
  }
  __syncthreads();
  int c = (t < BUCK_W) ? scnt[t] : 0;
  if (t < BUCK_W) soff[t] = c;
  __syncthreads();
  for (int off = 1; off < BUCK_W; off <<= 1) {
    int u = 0;
    if (t >= off && t < BUCK_W) u = soff[t - off];
    __syncthreads();
    if (t < BUCK_W) soff[t] += u;
    __syncthreads();
  }
  if (t < BUCK_W) {
    int ex = soff[t] - c;                    // exclusive local offset
    int node = (b << BUCK_SHIFT) + t;
    if (node < N_NODES) {
      cnt[node] = c;
      cursor[node] = s0 + ex;
      dinv[node] = rsqrtf((float)(c + 1));
    }
    scur[t] = ex;                            // running cursor starts at exclusive offset
  }
  __syncthreads();
  for (int i = t; i < len; i += 256) {
    unsigned u = (i < SEG_CAP) ? se[i] : sorted[s0 + i];
    int dl = u & (BUCK_W - 1);
    int r = atomicAdd(&scur[dl], 1);
    csr[s0 + r] = (int)(u >> BUCK_SHIFT);
  }
}

// ---- plain count (fallback path) ----
__global__ void k_count(const int* ei, const int* flag, int* cnt) {
  int e = blockIdx.x * blockDim.x + threadIdx.x;
  if (e >= N_EDGES) return;
  int f = *flag;
  atomicAdd(&cnt[edge_at(ei, 1, e, f)], 1);
}

// ---- dinv (fallback path) ----
__global__ void k_dinv(const int* cnt, float* dinv) {
  int t = blockIdx.x * blockDim.x + threadIdx.x;
  if (t < N_NODES) dinv[t] = rsqrtf((float)(cnt[t] + 1));
}

// ---- FUSED agg1 + gemm2: gather pre-scaled G1 -> h in reg ->
//      G2[n,j] = (sum_k shfl(h,k)*W2[k,j]) * dinv[n], bf16 out.
//      16-deep gather unroll: all row loads issued before accumulation (MLP);
//      W2/b1 loads moved AFTER the gather loop to keep in-loop VGPR pressure low. ----
__global__ void __launch_bounds__(256) k_agg1f(const __hip_bfloat16* G, const int* cursor,
                                               const int* cnt, const int* csr, const float* dinv,
                                               const float* b1, const float* W2,
                                               __hip_bfloat16* G2) {
  int j = threadIdx.x & 31, g = threadIdx.x >> 5;
  int n = blockIdx.x * 8 + g;
  if (n >= N_NODES) return;
  int len = cnt[n];
  int st = cursor[n];
  float dn = dinv[n];
  float acc = bf2f(G[n * 32 + j]);        // self loop (pre-scaled)
  int i = 0;
  for (; i + 16 <= len; i += 16) {
    int s[16];
    #pragma unroll
    for (int q = 0; q < 16; q++) s[q] = csr[st + i + q];
    float v[16];
    #pragma unroll
    for (int q = 0; q < 16; q++) v[q] = bf2f(G[s[q] * 32 + j]);
    #pragma unroll
    for (int q = 0; q < 16; q++) acc += v[q];
  }
  for (; i + 4 <= len; i += 4) {
    int s[4];
    #pragma unroll
    for (int q = 0; q < 4; q++) s[q] = csr[st + i + q];
    float v[4];
    #pragma unroll
    for (int q = 0; q < 4; q++) v[q] = bf2f(G[s[q] * 32 + j]);
    #pragma unroll
    for (int q = 0; q < 4; q++) acc += v[q];
  }
  for (; i < len; i++) acc += bf2f(G[csr[st + i] * 32 + j]);
  float h = fmaxf(dn * acc + b1[j], 0.0f);
  float g2 = 0.0f;
  #pragma unroll
  for (int k = 0; k < HID; k++) {
    float wk = (j < NCLUS) ? W2[k * NCLUS + j] : 0.0f;   // L1-hot after first group
    g2 += __shfl(h, k, 32) * wk;
  }
  G2[n * 32 + j] = __float2bfloat16((j < NCLUS) ? g2 * dn : 0.0f);
}

// ---- CSR agg layer2 (pre-scaled G2), 16-deep gather + softmax -> out + fx8 ----
__global__ void __launch_bounds__(256) k_agg2c(const __hip_bfloat16* G, const int* cursor,
                                               const int* cnt, const int* csr, const float* dinv,
                                               const float* b2, float* outp, unsigned char* fx8) {
  int j = threadIdx.x & 31, g = threadIdx.x >> 5;
  int n = blockIdx.x * 8 + g;
  if (n >= N_NODES) return;
  int len = cnt[n];
  int st = cursor[n];
  float acc = bf2f(G[n * 32 + j]);
  int i = 0;
  for (; i + 16 <= len; i += 16) {
    int s[16];
    #pragma unroll
    for (int q = 0; q < 16; q++) s[q] = csr[st + i + q];
    float v[16];
    #pragma unroll
    for (int q = 0; q < 16; q++) v[q] = bf2f(G[s[q] * 32 + j]);
    #pragma unroll
    for (int q = 0; q < 16; q++) acc += v[q];
  }
  for (; i + 4 <= len; i += 4) {
    int s[4];
    #pragma unroll
    for (int q = 0; q < 4; q++) s[q] = csr[st + i + q];
    float v[4];
    #pragma unroll
    for (int q = 0; q < 4; q++) v[q] = bf2f(G[s[q] * 32 + j]);
    #pragma unroll
    for (int q = 0; q < 4; q++) acc += v[q];
  }
  for (; i < len; i++) acc += bf2f(G[csr[st + i] * 32 + j]);
  bool act = (j < NCLUS);
  float logit = act ? fminf(fmaxf(dinv[n] * acc + b2[j], -80.0f), 80.0f) : -1e30f;
  float m = logit;
  #pragma unroll
  for (int mask = 16; mask > 0; mask >>= 1) m = fmaxf(m, __shfl_xor(m, mask, 32));
  float ex = act ? __expf(logit - m) : 0.0f;
  float ssum = ex;
  #pragma unroll
  for (int mask = 16; mask > 0; mask >>= 1) ssum += __shfl_xor(ssum, mask, 32);
  float fx = ex / fmaxf(ssum, 1e-30f);
  if (act) outp[n * NCLUS + j] = fx;
  fx8[n * 32 + j] = enc8(act ? fx : 0.0f);
}

// ---- fallback fp32 kernels (atomic path) ----
__global__ void __launch_bounds__(256) k_gemm1s(const float* x, const float* W1,
                                                const float* dinv, float* G1) {
  __shared__ float Ws[IN_DIM * HID];
  int tid = threadIdx.x;
  for (int i = tid; i < IN_DIM * HID; i += 256) Ws[i] = W1[i];
  __syncthreads();
  int j = tid & 31, r = tid >> 5;
  int n = blockIdx.x * 8 + r;
  if (n >= N_NODES) return;
  const float* xr = x + (size_t)n * IN_DIM;
  float acc = 0.0f;
  #pragma unroll
  for (int k = 0; k < IN_DIM; k++) acc += xr[k] * Ws[k * HID + j];
  G1[n * 32 + j] = acc * dinv[n];
}

__global__ void __launch_bounds__(256) k_gemm2s(const float* h, const float* W2,
                                                const float* dinv, float* G2) {
  __shared__ float Ws[HID * 32];
  int tid = threadIdx.x;
  for (int i = tid; i < HID * 32; i += 256) Ws[i] = 0.0f;
  __syncthreads();
  for (int i = tid; i < HID * NCLUS; i += 256) {
    int k = i / NCLUS, j = i % NCLUS;
    Ws[k * 32 + j] = W2[i];
  }
  __syncthreads();
  int j = tid & 31, r = tid >> 5;
  int n = blockIdx.x * 8 + r;
  if (n >= N_NODES) return;
  const float* hr = h + (size_t)n * 32;
  float acc = 0.0f;
  #pragma unroll
  for (int k = 0; k < HID; k++) acc += hr[k] * Ws[k * 32 + j];
  G2[n * 32 + j] = (j < NCLUS) ? acc * dinv[n] : 0.0f;
}

__global__ void __launch_bounds__(256) k_eagg2(const int* ei, const int* flag,
                                               const float* G, float* D) {
  int j = threadIdx.x & 31, g = threadIdx.x >> 5;
  int f = *flag;
  for (int e = blockIdx.x * 8 + g; e < N_EDGES; e += gridDim.x * 8) {
    int s = edge_at(ei, 0, e, f);
    int d = edge_at(ei, 1, e, f);
    atomicAdd(&D[d * 32 + j], G[s * 32 + j]);
  }
}

__global__ void k_relu2(const float* A, const float* dinv, const float* b1, float* G) {
  int t = blockIdx.x * blockDim.x + threadIdx.x;
  if (t >= N_NODES * 32) return;
  int n = t >> 5, j = t & 31;
  G[t] = fmaxf(dinv[n] * (A[t] + G[t]) + b1[j], 0.0f);
}

__global__ void __launch_bounds__(256) k_softmax2(const float* S, const float* G2, const float* dinv,
                                                  const float* b2, float* outp) {
  int n = blockIdx.x * blockDim.x + threadIdx.x;
  if (n >= N_NODES) return;
  float di = dinv[n];
  float lg[NCLUS];
  float m = -1e30f;
  #pragma unroll
  for (int j = 0; j < NCLUS; j++) {
    float v = di * (S[n * 32 + j] + G2[n * 32 + j]) + b2[j];
    v = fminf(fmaxf(v, -80.0f), 80.0f);
    lg[j] = v; m = fmaxf(m, v);
  }
  float ssum = 0.0f;
  #pragma unroll
  for (int j = 0; j < NCLUS; j++) { lg[j] = __expf(lg[j] - m); ssum += lg[j]; }
  float inv = 1.0f / ssum;
  #pragma unroll
  for (int j = 0; j < NCLUS; j++) outp[n * NCLUS + j] = lg[j] * inv;
}

// ---- out (fp32, stride 30) -> fx8 (fp8, stride 32), fallback path ----
__global__ void k_fx8(const float* outp, unsigned char* fx8) {
  int t = blockIdx.x * blockDim.x + threadIdx.x;
  if (t >= N_NODES * 32) return;
  int n = t >> 5, j = t & 31;
  fx8[t] = enc8((j < NCLUS) ? outp[n * NCLUS + j] : 0.0f);
}

// ---- edge MSE, lane-per-edge over fp8 rows (32 B/row, L2-resident 3.2 MB table) ----
__global__ void __launch_bounds__(256) k_msef3(const int* ei, const float* ep,
                                               const uint4* fx8, const int* flag,
                                               double* msed) {
  int f = *flag;
  int tid = blockIdx.x * blockDim.x + threadIdx.x;
  float local = 0.0f;
  for (int e = tid; e < N_EDGES; e += gridDim.x * blockDim.x) {
    int s = edge_at(ei, 0, e, f);
    int d = edge_at(ei, 1, e, f);
    const uint4* rs = fx8 + s * 2;   // 32 B row = 2 x uint4
    const uint4* rd = fx8 + d * 2;
    uint4 a0 = rs[0], a1 = rs[1];
    uint4 b0 = rd[0], b1 = rd[1];
    float acc;
    acc  = dot4_fp8(a0.x, b0.x) + dot4_fp8(a0.y, b0.y)
         + dot4_fp8(a0.z, b0.z) + dot4_fp8(a0.w, b0.w);
    acc += dot4_fp8(a1.x, b1.x) + dot4_fp8(a1.y, b1.y)
         + dot4_fp8(a1.z, b1.z) + dot4_fp8(a1.w, b1.w);
    float diff = acc - ep[e];
    local += diff * diff;
  }
  __shared__ float sd[256];
  sd[threadIdx.x] = local; __syncthreads();
  for (int off = 128; off > 0; off >>= 1) {
    if (threadIdx.x < off) sd[threadIdx.x] += sd[threadIdx.x + off];
    __syncthreads();
  }
  if (threadIdx.x == 0) atomicAdd(msed, (double)sd[0]);
}

// ---- column sums of log(1-FX^2) ----
__global__ void __launch_bounds__(256) k_colsumf(const float* FX, float* colsum) {
  __shared__ float sd[256];
  int tid = threadIdx.x;
  int j = tid & 31, g = tid >> 5;
  float local = 0.0f;
  if (j < NCLUS) {
    for (int n = blockIdx.x * 8 + g; n < N_NODES; n += gridDim.x * 8) {
      float v = FX[n * NCLUS + j];
      local += log1pf(-v * v);
    }
  }
  sd[tid] = local; __syncthreads();
  if (tid < 32) {
    float s = 0.0f;
    #pragma unroll
    for (int gg = 0; gg < 8; gg++) s += sd[tid + 32 * gg];
    if (tid < NCLUS) atomicAdd(&colsum[tid], s);
  }
}

// ---- final loss ----
__global__ void k_final(const float* colsum, const double* msed, float* out) {
  int tid = threadIdx.x;
  float v = 0.0f;
  if (tid < NCLUS) v = logf(1.0001f - __expf(colsum[tid]));
  #pragma unroll
  for (int mask = 32; mask > 0; mask >>= 1) v += __shfl_xor(v, mask, 64);
  if (tid == 0) {
    float preg = -v;
    float msev = (float)(*msed / (double)N_EDGES);
    out[(size_t)N_NODES * NCLUS] = msev + 0.01f * preg;
  }
}

extern "C" void kernel_launch(void* const* d_in, const int* in_sizes, int n_in,
                              void* d_out, int out_size, void* d_ws, size_t ws_size,
                              hipStream_t stream) {
  const float* x  = (const float*)d_in[0];
  const int*   ei = (const int*)d_in[1];
  const float* ep = (const float*)d_in[2];
  const float* W1 = (const float*)d_in[3];
  const float* b1 = (const float*)d_in[4];
  const float* W2 = (const float*)d_in[5];
  const float* b2 = (const float*)d_in[6];
  float* out = (float*)d_out;   // fp32: FX[100000*30] then loss scalar

  char* ws = (char*)d_ws;
  size_t off = 0;
  auto alloc = [&](size_t bytes) { size_t o = off; off += (bytes + 255) & ~(size_t)255; return o; };

  size_t o_hdr  = alloc(1024);                       // flag@0, msed@8(double), colsum@256
  size_t o_cnt  = alloc((size_t)N_NODES * 4);
  size_t o_dinv = alloc((size_t)N_NODES * 4);
  size_t o_B1   = alloc((size_t)N_NODES * 32 * 4);   // CSR: G1 bf16 [0,6.4M) + H/tot/bstart [6.4M,...)
  size_t o_B2   = alloc((size_t)N_NODES * 32 * 4);   // CSR: sorted [0,12.8M) -> later fx8[0,3.2M)+G2[3.2M,9.6M)

  int*    flag   = (int*)(ws + o_hdr);
  double* msed   = (double*)(ws + o_hdr + 8);
  float*  colsum = (float*)(ws + o_hdr + 256);
  int*    cnt    = (int*)(ws + o_cnt);
  float*  dinv   = (float*)(ws + o_dinv);
  float*  B1f    = (float*)(ws + o_B1);
  float*  B2f    = (float*)(ws + o_B2);
  __hip_bfloat16* B1b = (__hip_bfloat16*)(ws + o_B1);
  unsigned char*  B2c = (unsigned char*)(ws + o_B2);

  const int nodeBlocks = (N_NODES + 255) / 256;
  const int edgeBlocks = EDGE_BLOCKS;
  const int grpBlocks  = GRP_BLOCKS;
  const int elemBlocks = (N_NODES * 32 + 255) / 256;

  k_detect<<<1, 64, 0, stream>>>((const unsigned int*)ei, flag);

  size_t o_cursor = alloc((size_t)N_NODES * 4);
  size_t o_csr    = alloc((size_t)N_EDGES * 4);
  bool use_csr = (off <= ws_size);

  const unsigned char* fx8;

  if (use_csr) {
    int* cursor = (int*)(ws + o_cursor);
    int* csr    = (int*)(ws + o_csr);
    // overlays inside B1 upper half (G1 bf16 occupies [0, 6.4M))
    int* H      = (int*)(ws + o_B1 + 6400000);                 // 512*782*4 = 1.6 MB
    int* tot    = (int*)(ws + o_B1 + 6400000 + 1601536);       // 782*4
    int* bstart = (int*)(ws + o_B1 + 6400000 + 1605632);       // 783*4
    unsigned* sorted = (unsigned*)B2c;                          // B2 [0,12.8M), dead after pass2

    k_zerosc<<<1, 64, 0, stream>>>(colsum, msed);

    // LDS-atomic counting sort -> cnt, cursor, dinv, csr (zero global atomics)
    k_hist <<<PB, 256, 0, stream>>>(ei, flag, H);
    k_hscan<<<NBUCK, PB, 0, stream>>>(H, tot);
    k_bscan<<<1, 1024, 0, stream>>>(tot, bstart);
    k_scat1<<<PB, 256, 0, stream>>>(ei, flag, H, bstart, sorted);
    k_pass2<<<NBUCK, 256, 0, stream>>>(sorted, bstart, cnt, cursor, dinv, csr);

    // gemm1 after the sort: writes dinv-pre-scaled G1
    __hip_bfloat16* G1b = B1b;
    k_gemm1r<<<G1_BLOCKS, 256, 0, stream>>>(x, W1, dinv, G1b);

    __hip_bfloat16* G2b = (__hip_bfloat16*)(ws + o_B2 + (size_t)N_NODES * 32); // [3.2M,9.6M)
    unsigned char*  fx  = B2c;                                                  // [0,3.2M)

    k_agg1f<<<grpBlocks, 256, 0, stream>>>(G1b, cursor, cnt, csr, dinv, b1, W2, G2b);
    k_agg2c<<<grpBlocks, 256, 0, stream>>>(G2b, cursor, cnt, csr, dinv, b2, out, fx);
    fx8 = fx;
  } else {
    k_zeroall<<<nodeBlocks, 256, 0, stream>>>(cnt, colsum, msed);
    k_count<<<edgeBlocks, 256, 0, stream>>>(ei, flag, cnt);
    k_dinv<<<nodeBlocks, 256, 0, stream>>>(cnt, dinv);
    k_gemm1s<<<grpBlocks, 256, 0, stream>>>(x, W1, dinv, B1f);
    hipMemsetAsync(B2f, 0, (size_t)N_NODES * 32 * 4, stream);
    k_eagg2<<<8192, 256, 0, stream>>>(ei, flag, B1f, B2f);
    k_relu2<<<elemBlocks, 256, 0, stream>>>(B2f, dinv, b1, B1f);
    k_gemm2s<<<grpBlocks, 256, 0, stream>>>(B1f, W2, dinv, B2f);
    hipMemsetAsync(B1f, 0, (size_t)N_NODES * 32 * 4, stream);
    k_eagg2<<<8192, 256, 0, stream>>>(ei, flag, B2f, B1f);
    k_softmax2<<<nodeBlocks, 256, 0, stream>>>(B1f, B2f, dinv, b2, out);
    k_fx8<<<elemBlocks, 256, 0, stream>>>(out, (unsigned char*)B1b);
    fx8 = (const unsigned char*)B1b;
  }

  // loss
  k_msef3<<<4096, 256, 0, stream>>>(ei, ep, (const uint4*)fx8, flag, msed);
  k_colsumf<<<256, 256, 0, stream>>>(out, colsum);
  k_final<<<1, 64, 0, stream>>>(colsum, msed, out);
}

// Round 6
// 483.689 us; speedup vs baseline: 1.1592x; 1.0340x over previous
//
#include <hip/hip_runtime.h>
#include <hip/hip_bf16.h>
#include <hip/hip_fp8.h>

#define N_NODES 100000
#define N_EDGES 3200000
#define IN_DIM  128
#define HID     32
#define NCLUS   30
#define EDGE_BLOCKS 12500 // ceil(3200000/256)
#define GRP_BLOCKS  12500 // ceil(100000/8)

// ---- counting-sort geometry (LDS-atomic CSR build; global atomics eliminated) ----
#define BUCK_SHIFT 7
#define BUCK_W     128                 // nodes per bucket
#define NBUCK      782                 // ceil(100000/128)
#define PB         512                 // pass-1 blocks
#define EPB        6250                // edges per pass-1 block (512*6250 = 3.2M exact)
#define SEG_CAP    8192                // LDS stage capacity per bucket (avg 4092, 64 sigma margin)

// ---- gemm1 register-blocked geometry ----
// R5 post-mortem: 32 pairs/wave -> only 391 blocks -> 1.5 waves/SIMD -> 15% occupancy,
// latency-bound at 370 GB/s. 8 pairs/wave -> 1563 blocks -> ~6 waves/SIMD.
#define G1_PAIRS   8                   // row-pairs per wave
#define G1_ROWS_PER_BLOCK 64           // 4 waves * 2 rows * 8 pairs
#define G1_BLOCKS  1563                // ceil(100000/64)

__device__ __forceinline__ float bf2f(__hip_bfloat16 v) { return __bfloat162float(v); }

// fp8 e4m3 (OCP) encode/decode via HW cvt
__device__ __forceinline__ unsigned char enc8(float v) {
  __hip_fp8_e4m3 t(v); return (unsigned char)t.__x;
}
__device__ __forceinline__ float dec8(unsigned b) {
  __hip_fp8_e4m3 t; t.__x = (__hip_fp8_storage_t)b; return (float)t;
}
__device__ __forceinline__ float dot4_fp8(unsigned a, unsigned b) {
  float r = 0.0f;
  #pragma unroll
  for (int k = 0; k < 4; k++)
    r += dec8((a >> (8 * k)) & 0xffu) * dec8((b >> (8 * k)) & 0xffu);
  return r;
}

// edge_index accessor: f=0 -> int32 layout, f=1 -> int64 layout (read low word)
__device__ __forceinline__ int edge_at(const int* ei, int row, int e, int f) {
  int v = ei[(row * N_EDGES + e) << f];
  return min(max(v, 0), N_NODES - 1);
}

// ---- detect int32 vs int64 edge_index ----
__global__ void k_detect(const unsigned int* ei, int* flag) {
  if (threadIdx.x == 0) {
    int zeros = 0;
    for (int i = 1; i < 128; i += 2) zeros += (ei[i] == 0u) ? 1 : 0;
    *flag = (zeros >= 48) ? 1 : 0;
  }
}

// ---- zero loss scalars (CSR path needs no counter zeroing: pass2 writes all nodes) ----
__global__ void k_zerosc(float* colsum, double* msed) {
  int t = threadIdx.x;
  if (t < 32) colsum[t] = 0.0f;
  if (t == 32) *msed = 0.0;
}

// ---- zero cnt + loss scalars (fallback path) ----
__global__ void k_zeroall(int* cnt, float* colsum, double* msed) {
  int t = blockIdx.x * blockDim.x + threadIdx.x;
  if (t < N_NODES) cnt[t] = 0;
  if (t < 32) colsum[t] = 0.0f;
  if (t == 32) *msed = 0.0;
}

// ---- GEMM1 v4: register-blocked + PRE-SCALED by dinv[n]; 8 pairs/wave for occupancy ----
__global__ void __launch_bounds__(256) k_gemm1r(const float* x, const float* W1,
                                                const float* dinv, __hip_bfloat16* G1) {
  int lane = threadIdx.x & 63;
  int wid  = threadIdx.x >> 6;
  int j = lane & 31;                     // output col
  int h = lane >> 5;                     // k-half: 0 -> k in [0,64), 1 -> [64,128)
  float w[64];
  #pragma unroll
  for (int k = 0; k < 64; k++) w[k] = W1[(h * 64 + k) * HID + j];   // L1-hot, coalesced per half
  int base = (blockIdx.x * 4 + wid) * (2 * G1_PAIRS);
  #pragma unroll
  for (int p = 0; p < G1_PAIRS; p++) {
    int n0 = base + 2 * p;
    if (n0 >= N_NODES) return;
    int n1 = n0 + 1;                     // N_NODES even -> always valid
    const float4* xa = (const float4*)(x + (size_t)n0 * IN_DIM + h * 64);
    const float4* xb = (const float4*)(x + (size_t)n1 * IN_DIM + h * 64);
    float accA = 0.0f, accB = 0.0f;
    #pragma unroll
    for (int c = 0; c < 16; c++) {
      float4 a = xa[c];
      float4 b = xb[c];
      accA += a.x * w[4*c] + a.y * w[4*c+1] + a.z * w[4*c+2] + a.w * w[4*c+3];
      accB += b.x * w[4*c] + b.y * w[4*c+1] + b.z * w[4*c+2] + b.w * w[4*c+3];
    }
    accA += __shfl_xor(accA, 32, 64);    // combine K-halves
    accB += __shfl_xor(accB, 32, 64);
    if (h == 0) G1[n0 * 32 + j] = __float2bfloat16(accA * dinv[n0]);
    else        G1[n1 * 32 + j] = __float2bfloat16(accB * dinv[n1]);
  }
}

// ---- sort pass 1a: per-block LDS bucket histogram (dst>>7), dump H[p][*] ----
__global__ void __launch_bounds__(256) k_hist(const int* ei, const int* flag, int* H) {
  __shared__ int h[NBUCK];
  int t = threadIdx.x, p = blockIdx.x;
  for (int i = t; i < NBUCK; i += 256) h[i] = 0;
  __syncthreads();
  int f = *flag;
  int base = p * EPB;
  for (int i = t; i < EPB; i += 256) {
    int d = edge_at(ei, 1, base + i, f);
    atomicAdd(&h[d >> BUCK_SHIFT], 1);       // ds_add, on-CU
  }
  __syncthreads();
  for (int i = t; i < NBUCK; i += 256) H[p * NBUCK + i] = h[i];
}

// ---- sort scan A: column-scan of H over PB blocks -> exclusive in place + bucket totals ----
__global__ void __launch_bounds__(PB) k_hscan(int* H, int* tot) {
  __shared__ int s[PB];
  int b = blockIdx.x, t = threadIdx.x;
  int v = H[t * NBUCK + b];
  s[t] = v; __syncthreads();
  for (int off = 1; off < PB; off <<= 1) {
    int u = (t >= off) ? s[t - off] : 0;
    __syncthreads();
    s[t] += u;
    __syncthreads();
  }
  H[t * NBUCK + b] = s[t] - v;               // exclusive prefix within bucket column
  if (t == PB - 1) tot[b] = s[t];
}

// ---- sort scan B: exclusive scan of bucket totals -> bstart[0..NBUCK] ----
__global__ void __launch_bounds__(1024) k_bscan(const int* tot, int* bstart) {
  __shared__ int s[1024];
  int t = threadIdx.x;
  int v = (t < NBUCK) ? tot[t] : 0;
  s[t] = v; __syncthreads();
  for (int off = 1; off < 1024; off <<= 1) {
    int u = (t >= off) ? s[t - off] : 0;
    __syncthreads();
    s[t] += u;
    __syncthreads();
  }
  if (t < NBUCK) bstart[t] = s[t] - v;
  if (t == NBUCK - 1) bstart[NBUCK] = s[t];  // = N_EDGES
}

// ---- sort pass 1b: scatter packed (src<<7 | dst&127) to bucket-segmented order ----
__global__ void __launch_bounds__(256) k_scat1(const int* ei, const int* flag, const int* H,
                                               const int* bstart, unsigned* sorted) {
  __shared__ int cur[NBUCK];
  int t = threadIdx.x, p = blockIdx.x;
  for (int i = t; i < NBUCK; i += 256) cur[i] = bstart[i] + H[p * NBUCK + i];
  __syncthreads();
  int f = *flag;
  int base = p * EPB;
  for (int i = t; i < EPB; i += 256) {
    int e = base + i;
    int s = edge_at(ei, 0, e, f);
    int d = edge_at(ei, 1, e, f);
    int slot = atomicAdd(&cur[d >> BUCK_SHIFT], 1);   // ds_add_rtn, on-CU
    sorted[slot] = ((unsigned)s << BUCK_SHIFT) | (unsigned)(d & (BUCK_W - 1));
  }
}

// ---- sort pass 2: one block per bucket: LDS count + scan -> cnt/cursor/dinv + exact CSR ----
__global__ void __launch_bounds__(256) k_pass2(const unsigned* sorted, const int* bstart,
                                               int* cnt, int* cursor, float* dinv, int* csr) {
  __shared__ unsigned se[SEG_CAP];
  __shared__ int scnt[BUCK_W], soff[BUCK_W], scur[BUCK_W];
  int b = blockIdx.x, t = threadIdx.x;
  int s0 = bstart[b], s1 = bstart[b + 1], len = s1 - s0;
  for (int i = t; i < len && i < SEG_CAP; i += 256) se[i] = sorted[s0 + i];
  if (t < BUCK_W) scnt[t] = 0;
  __syncthreads();
  for (int i = t; i < len; i += 256) {
    unsigned u = (i < SEG_CAP) ? se[i] : sorted[s0 + i];
    atomicAdd(&scnt[u & (BUCK_W - 1)], 1);
  }
  __syncthreads();
  int c = (t < BUCK_W) ? scnt[t] : 0;
  if (t < BUCK_W) soff[t] = c;
  __syncthreads();
  for (int off = 1; off < BUCK_W; off <<= 1) {
    int u = 0;
    if (t >= off && t < BUCK_W) u = soff[t - off];
    __syncthreads();
    if (t < BUCK_W) soff[t] += u;
    __syncthreads();
  }
  if (t < BUCK_W) {
    int ex = soff[t] - c;                    // exclusive local offset
    int node = (b << BUCK_SHIFT) + t;
    if (node < N_NODES) {
      cnt[node] = c;
      cursor[node] = s0 + ex;
      dinv[node] = rsqrtf((float)(c + 1));
    }
    scur[t] = ex;                            // running cursor starts at exclusive offset
  }
  __syncthreads();
  for (int i = t; i < len; i += 256) {
    unsigned u = (i < SEG_CAP) ? se[i] : sorted[s0 + i];
    int dl = u & (BUCK_W - 1);
    int r = atomicAdd(&scur[dl], 1);
    csr[s0 + r] = (int)(u >> BUCK_SHIFT);
  }
}

// ---- plain count (fallback path) ----
__global__ void k_count(const int* ei, const int* flag, int* cnt) {
  int e = blockIdx.x * blockDim.x + threadIdx.x;
  if (e >= N_EDGES) return;
  int f = *flag;
  atomicAdd(&cnt[edge_at(ei, 1, e, f)], 1);
}

// ---- dinv (fallback path) ----
__global__ void k_dinv(const int* cnt, float* dinv) {
  int t = blockIdx.x * blockDim.x + threadIdx.x;
  if (t < N_NODES) dinv[t] = rsqrtf((float)(cnt[t] + 1));
}

// ---- FUSED agg1 + gemm2: gather pre-scaled G1 -> h in reg ->
//      G2[n,j] = (sum_k shfl(h,k)*W2[k,j]) * dinv[n], bf16 out.
//      16-deep gather unroll: all row loads issued before accumulation (MLP). ----
__global__ void __launch_bounds__(256) k_agg1f(const __hip_bfloat16* G, const int* cursor,
                                               const int* cnt, const int* csr, const float* dinv,
                                               const float* b1, const float* W2,
                                               __hip_bfloat16* G2) {
  int j = threadIdx.x & 31, g = threadIdx.x >> 5;
  int n = blockIdx.x * 8 + g;
  if (n >= N_NODES) return;
  int len = cnt[n];
  int st = cursor[n];
  float dn = dinv[n];
  float acc = bf2f(G[n * 32 + j]);        // self loop (pre-scaled)
  int i = 0;
  for (; i + 16 <= len; i += 16) {
    int s[16];
    #pragma unroll
    for (int q = 0; q < 16; q++) s[q] = csr[st + i + q];
    float v[16];
    #pragma unroll
    for (int q = 0; q < 16; q++) v[q] = bf2f(G[s[q] * 32 + j]);
    #pragma unroll
    for (int q = 0; q < 16; q++) acc += v[q];
  }
  for (; i + 4 <= len; i += 4) {
    int s[4];
    #pragma unroll
    for (int q = 0; q < 4; q++) s[q] = csr[st + i + q];
    float v[4];
    #pragma unroll
    for (int q = 0; q < 4; q++) v[q] = bf2f(G[s[q] * 32 + j]);
    #pragma unroll
    for (int q = 0; q < 4; q++) acc += v[q];
  }
  for (; i < len; i++) acc += bf2f(G[csr[st + i] * 32 + j]);
  float h = fmaxf(dn * acc + b1[j], 0.0f);
  float g2 = 0.0f;
  #pragma unroll
  for (int k = 0; k < HID; k++) {
    float wk = (j < NCLUS) ? W2[k * NCLUS + j] : 0.0f;   // L1-hot after first group
    g2 += __shfl(h, k, 32) * wk;
  }
  G2[n * 32 + j] = __float2bfloat16((j < NCLUS) ? g2 * dn : 0.0f);
}

// ---- CSR agg layer2 (pre-scaled G2), 16-deep gather + softmax -> out + fx8 ----
__global__ void __launch_bounds__(256) k_agg2c(const __hip_bfloat16* G, const int* cursor,
                                               const int* cnt, const int* csr, const float* dinv,
                                               const float* b2, float* outp, unsigned char* fx8) {
  int j = threadIdx.x & 31, g = threadIdx.x >> 5;
  int n = blockIdx.x * 8 + g;
  if (n >= N_NODES) return;
  int len = cnt[n];
  int st = cursor[n];
  float acc = bf2f(G[n * 32 + j]);
  int i = 0;
  for (; i + 16 <= len; i += 16) {
    int s[16];
    #pragma unroll
    for (int q = 0; q < 16; q++) s[q] = csr[st + i + q];
    float v[16];
    #pragma unroll
    for (int q = 0; q < 16; q++) v[q] = bf2f(G[s[q] * 32 + j]);
    #pragma unroll
    for (int q = 0; q < 16; q++) acc += v[q];
  }
  for (; i + 4 <= len; i += 4) {
    int s[4];
    #pragma unroll
    for (int q = 0; q < 4; q++) s[q] = csr[st + i + q];
    float v[4];
    #pragma unroll
    for (int q = 0; q < 4; q++) v[q] = bf2f(G[s[q] * 32 + j]);
    #pragma unroll
    for (int q = 0; q < 4; q++) acc += v[q];
  }
  for (; i < len; i++) acc += bf2f(G[csr[st + i] * 32 + j]);
  bool act = (j < NCLUS);
  float logit = act ? fminf(fmaxf(dinv[n] * acc + b2[j], -80.0f), 80.0f) : -1e30f;
  float m = logit;
  #pragma unroll
  for (int mask = 16; mask > 0; mask >>= 1) m = fmaxf(m, __shfl_xor(m, mask, 32));
  float ex = act ? __expf(logit - m) : 0.0f;
  float ssum = ex;
  #pragma unroll
  for (int mask = 16; mask > 0; mask >>= 1) ssum += __shfl_xor(ssum, mask, 32);
  float fx = ex / fmaxf(ssum, 1e-30f);
  if (act) outp[n * NCLUS + j] = fx;
  fx8[n * 32 + j] = enc8(act ? fx : 0.0f);
}

// ---- fallback fp32 kernels (atomic path) ----
__global__ void __launch_bounds__(256) k_gemm1s(const float* x, const float* W1,
                                                const float* dinv, float* G1) {
  __shared__ float Ws[IN_DIM * HID];
  int tid = threadIdx.x;
  for (int i = tid; i < IN_DIM * HID; i += 256) Ws[i] = W1[i];
  __syncthreads();
  int j = tid & 31, r = tid >> 5;
  int n = blockIdx.x * 8 + r;
  if (n >= N_NODES) return;
  const float* xr = x + (size_t)n * IN_DIM;
  float acc = 0.0f;
  #pragma unroll
  for (int k = 0; k < IN_DIM; k++) acc += xr[k] * Ws[k * HID + j];
  G1[n * 32 + j] = acc * dinv[n];
}

__global__ void __launch_bounds__(256) k_gemm2s(const float* h, const float* W2,
                                                const float* dinv, float* G2) {
  __shared__ float Ws[HID * 32];
  int tid = threadIdx.x;
  for (int i = tid; i < HID * 32; i += 256) Ws[i] = 0.0f;
  __syncthreads();
  for (int i = tid; i < HID * NCLUS; i += 256) {
    int k = i / NCLUS, j = i % NCLUS;
    Ws[k * 32 + j] = W2[i];
  }
  __syncthreads();
  int j = tid & 31, r = tid >> 5;
  int n = blockIdx.x * 8 + r;
  if (n >= N_NODES) return;
  const float* hr = h + (size_t)n * 32;
  float acc = 0.0f;
  #pragma unroll
  for (int k = 0; k < HID; k++) acc += hr[k] * Ws[k * 32 + j];
  G2[n * 32 + j] = (j < NCLUS) ? acc * dinv[n] : 0.0f;
}

__global__ void __launch_bounds__(256) k_eagg2(const int* ei, const int* flag,
                                               const float* G, float* D) {
  int j = threadIdx.x & 31, g = threadIdx.x >> 5;
  int f = *flag;
  for (int e = blockIdx.x * 8 + g; e < N_EDGES; e += gridDim.x * 8) {
    int s = edge_at(ei, 0, e, f);
    int d = edge_at(ei, 1, e, f);
    atomicAdd(&D[d * 32 + j], G[s * 32 + j]);
  }
}

__global__ void k_relu2(const float* A, const float* dinv, const float* b1, float* G) {
  int t = blockIdx.x * blockDim.x + threadIdx.x;
  if (t >= N_NODES * 32) return;
  int n = t >> 5, j = t & 31;
  G[t] = fmaxf(dinv[n] * (A[t] + G[t]) + b1[j], 0.0f);
}

__global__ void __launch_bounds__(256) k_softmax2(const float* S, const float* G2, const float* dinv,
                                                  const float* b2, float* outp) {
  int n = blockIdx.x * blockDim.x + threadIdx.x;
  if (n >= N_NODES) return;
  float di = dinv[n];
  float lg[NCLUS];
  float m = -1e30f;
  #pragma unroll
  for (int j = 0; j < NCLUS; j++) {
    float v = di * (S[n * 32 + j] + G2[n * 32 + j]) + b2[j];
    v = fminf(fmaxf(v, -80.0f), 80.0f);
    lg[j] = v; m = fmaxf(m, v);
  }
  float ssum = 0.0f;
  #pragma unroll
  for (int j = 0; j < NCLUS; j++) { lg[j] = __expf(lg[j] - m); ssum += lg[j]; }
  float inv = 1.0f / ssum;
  #pragma unroll
  for (int j = 0; j < NCLUS; j++) outp[n * NCLUS + j] = lg[j] * inv;
}

// ---- out (fp32, stride 30) -> fx8 (fp8, stride 32), fallback path ----
__global__ void k_fx8(const float* outp, unsigned char* fx8) {
  int t = blockIdx.x * blockDim.x + threadIdx.x;
  if (t >= N_NODES * 32) return;
  int n = t >> 5, j = t & 31;
  fx8[t] = enc8((j < NCLUS) ? outp[n * NCLUS + j] : 0.0f);
}

// ---- edge MSE, lane-per-edge over fp8 rows (32 B/row, L2-resident 3.2 MB table) ----
__global__ void __launch_bounds__(256) k_msef3(const int* ei, const float* ep,
                                               const uint4* fx8, const int* flag,
                                               double* msed) {
  int f = *flag;
  int tid = blockIdx.x * blockDim.x + threadIdx.x;
  float local = 0.0f;
  for (int e = tid; e < N_EDGES; e += gridDim.x * blockDim.x) {
    int s = edge_at(ei, 0, e, f);
    int d = edge_at(ei, 1, e, f);
    const uint4* rs = fx8 + s * 2;   // 32 B row = 2 x uint4
    const uint4* rd = fx8 + d * 2;
    uint4 a0 = rs[0], a1 = rs[1];
    uint4 b0 = rd[0], b1 = rd[1];
    float acc;
    acc  = dot4_fp8(a0.x, b0.x) + dot4_fp8(a0.y, b0.y)
         + dot4_fp8(a0.z, b0.z) + dot4_fp8(a0.w, b0.w);
    acc += dot4_fp8(a1.x, b1.x) + dot4_fp8(a1.y, b1.y)
         + dot4_fp8(a1.z, b1.z) + dot4_fp8(a1.w, b1.w);
    float diff = acc - ep[e];
    local += diff * diff;
  }
  __shared__ float sd[256];
  sd[threadIdx.x] = local; __syncthreads();
  for (int off = 128; off > 0; off >>= 1) {
    if (threadIdx.x < off) sd[threadIdx.x] += sd[threadIdx.x + off];
    __syncthreads();
  }
  if (threadIdx.x == 0) atomicAdd(msed, (double)sd[0]);
}

// ---- column sums of log(1-FX^2) ----
__global__ void __launch_bounds__(256) k_colsumf(const float* FX, float* colsum) {
  __shared__ float sd[256];
  int tid = threadIdx.x;
  int j = tid & 31, g = tid >> 5;
  float local = 0.0f;
  if (j < NCLUS) {
    for (int n = blockIdx.x * 8 + g; n < N_NODES; n += gridDim.x * 8) {
      float v = FX[n * NCLUS + j];
      local += log1pf(-v * v);
    }
  }
  sd[tid] = local; __syncthreads();
  if (tid < 32) {
    float s = 0.0f;
    #pragma unroll
    for (int gg = 0; gg < 8; gg++) s += sd[tid + 32 * gg];
    if (tid < NCLUS) atomicAdd(&colsum[tid], s);
  }
}

// ---- final loss ----
__global__ void k_final(const float* colsum, const double* msed, float* out) {
  int tid = threadIdx.x;
  float v = 0.0f;
  if (tid < NCLUS) v = logf(1.0001f - __expf(colsum[tid]));
  #pragma unroll
  for (int mask = 32; mask > 0; mask >>= 1) v += __shfl_xor(v, mask, 64);
  if (tid == 0) {
    float preg = -v;
    float msev = (float)(*msed / (double)N_EDGES);
    out[(size_t)N_NODES * NCLUS] = msev + 0.01f * preg;
  }
}

extern "C" void kernel_launch(void* const* d_in, const int* in_sizes, int n_in,
                              void* d_out, int out_size, void* d_ws, size_t ws_size,
                              hipStream_t stream) {
  const float* x  = (const float*)d_in[0];
  const int*   ei = (const int*)d_in[1];
  const float* ep = (const float*)d_in[2];
  const float* W1 = (const float*)d_in[3];
  const float* b1 = (const float*)d_in[4];
  const float* W2 = (const float*)d_in[5];
  const float* b2 = (const float*)d_in[6];
  float* out = (float*)d_out;   // fp32: FX[100000*30] then loss scalar

  char* ws = (char*)d_ws;
  size_t off = 0;
  auto alloc = [&](size_t bytes) { size_t o = off; off += (bytes + 255) & ~(size_t)255; return o; };

  size_t o_hdr  = alloc(1024);                       // flag@0, msed@8(double), colsum@256
  size_t o_cnt  = alloc((size_t)N_NODES * 4);
  size_t o_dinv = alloc((size_t)N_NODES * 4);
  size_t o_B1   = alloc((size_t)N_NODES * 32 * 4);   // CSR: G1 bf16 [0,6.4M) + H/tot/bstart [6.4M,...)
  size_t o_B2   = alloc((size_t)N_NODES * 32 * 4);   // CSR: sorted [0,12.8M) -> later fx8[0,3.2M)+G2[3.2M,9.6M)

  int*    flag   = (int*)(ws + o_hdr);
  double* msed   = (double*)(ws + o_hdr + 8);
  float*  colsum = (float*)(ws + o_hdr + 256);
  int*    cnt    = (int*)(ws + o_cnt);
  float*  dinv   = (float*)(ws + o_dinv);
  float*  B1f    = (float*)(ws + o_B1);
  float*  B2f    = (float*)(ws + o_B2);
  __hip_bfloat16* B1b = (__hip_bfloat16*)(ws + o_B1);
  unsigned char*  B2c = (unsigned char*)(ws + o_B2);

  const int nodeBlocks = (N_NODES + 255) / 256;
  const int edgeBlocks = EDGE_BLOCKS;
  const int grpBlocks  = GRP_BLOCKS;
  const int elemBlocks = (N_NODES * 32 + 255) / 256;

  k_detect<<<1, 64, 0, stream>>>((const unsigned int*)ei, flag);

  size_t o_cursor = alloc((size_t)N_NODES * 4);
  size_t o_csr    = alloc((size_t)N_EDGES * 4);
  bool use_csr = (off <= ws_size);

  const unsigned char* fx8;

  if (use_csr) {
    int* cursor = (int*)(ws + o_cursor);
    int* csr    = (int*)(ws + o_csr);
    // overlays inside B1 upper half (G1 bf16 occupies [0, 6.4M))
    int* H      = (int*)(ws + o_B1 + 6400000);                 // 512*782*4 = 1.6 MB
    int* tot    = (int*)(ws + o_B1 + 6400000 + 1601536);       // 782*4
    int* bstart = (int*)(ws + o_B1 + 6400000 + 1605632);       // 783*4
    unsigned* sorted = (unsigned*)B2c;                          // B2 [0,12.8M), dead after pass2

    k_zerosc<<<1, 64, 0, stream>>>(colsum, msed);

    // LDS-atomic counting sort -> cnt, cursor, dinv, csr (zero global atomics)
    k_hist <<<PB, 256, 0, stream>>>(ei, flag, H);
    k_hscan<<<NBUCK, PB, 0, stream>>>(H, tot);
    k_bscan<<<1, 1024, 0, stream>>>(tot, bstart);
    k_scat1<<<PB, 256, 0, stream>>>(ei, flag, H, bstart, sorted);
    k_pass2<<<NBUCK, 256, 0, stream>>>(sorted, bstart, cnt, cursor, dinv, csr);

    // gemm1 after the sort: writes dinv-pre-scaled G1
    __hip_bfloat16* G1b = B1b;
    k_gemm1r<<<G1_BLOCKS, 256, 0, stream>>>(x, W1, dinv, G1b);

    __hip_bfloat16* G2b = (__hip_bfloat16*)(ws + o_B2 + (size_t)N_NODES * 32); // [3.2M,9.6M)
    unsigned char*  fx  = B2c;                                                  // [0,3.2M)

    k_agg1f<<<grpBlocks, 256, 0, stream>>>(G1b, cursor, cnt, csr, dinv, b1, W2, G2b);
    k_agg2c<<<grpBlocks, 256, 0, stream>>>(G2b, cursor, cnt, csr, dinv, b2, out, fx);
    fx8 = fx;
  } else {
    k_zeroall<<<nodeBlocks, 256, 0, stream>>>(cnt, colsum, msed);
    k_count<<<edgeBlocks, 256, 0, stream>>>(ei, flag, cnt);
    k_dinv<<<nodeBlocks, 256, 0, stream>>>(cnt, dinv);
    k_gemm1s<<<grpBlocks, 256, 0, stream>>>(x, W1, dinv, B1f);
    hipMemsetAsync(B2f, 0, (size_t)N_NODES * 32 * 4, stream);
    k_eagg2<<<8192, 256, 0, stream>>>(ei, flag, B1f, B2f);
    k_relu2<<<elemBlocks, 256, 0, stream>>>(B2f, dinv, b1, B1f);
    k_gemm2s<<<grpBlocks, 256, 0, stream>>>(B1f, W2, dinv, B2f);
    hipMemsetAsync(B1f, 0, (size_t)N_NODES * 32 * 4, stream);
    k_eagg2<<<8192, 256, 0, stream>>>(ei, flag, B2f, B1f);
    k_softmax2<<<nodeBlocks, 256, 0, stream>>>(B1f, B2f, dinv, b2, out);
    k_fx8<<<elemBlocks, 256, 0, stream>>>(out, (unsigned char*)B1b);
    fx8 = (const unsigned char*)B1b;
  }

  // loss
  k_msef3<<<4096, 256, 0, stream>>>(ei, ep, (const uint4*)fx8, flag, msed);
  k_colsumf<<<256, 256, 0, stream>>>(out, colsum);
  k_final<<<1, 64, 0, stream>>>(colsum, msed, out);
}